// Round 1
// baseline (434.854 us; speedup 1.0000x reference)
//
#include <hip/hip_runtime.h>
#include <cstdint>
#include <cstddef>

#define DEVI __device__ __forceinline__

typedef __attribute__((ext_vector_type(8))) short short8;
typedef __attribute__((ext_vector_type(4))) float f32x4;
typedef __attribute__((ext_vector_type(2))) unsigned short u16x2;
typedef __attribute__((ext_vector_type(4))) unsigned short u16x4;
typedef __attribute__((ext_vector_type(8))) unsigned short u16x8;

#define Bn 8
#define Cn 512
#define HWn 4096
#define Mtot 32768

DEVI float b2f(unsigned short u) {
  union { uint32_t u; float f; } c; c.u = ((uint32_t)u) << 16; return c.f;
}
DEVI unsigned short f2b(float f) {
  union { float f; uint32_t u; } c; c.f = f;
  uint32_t u = c.u + 0x7fffu + ((c.u >> 16) & 1u);
  return (unsigned short)(u >> 16);
}
DEVI float gelu_exact(float x) { return 0.5f * x * (1.0f + erff(x * 0.7071067811865476f)); }

DEVI void async16(const void* g, void* l) {
  __builtin_amdgcn_global_load_lds((const __attribute__((address_space(1))) uint32_t*)g,
                                   (__attribute__((address_space(3))) uint32_t*)l, 16, 0, 0);
}

// ---------------- NT GEMM core: C[128x128] = A[M,K] * B[N,K]^T, bf16 in, f32 acc.
// LDS tiles [128 rows][64 k] bf16, rows 128B = 8 x 16B slots, XOR-swizzle slot ^= (row&7).
DEVI void gemm_core(const unsigned short* __restrict__ A, const unsigned short* __restrict__ Bm,
                    int K, int m0, int n0, unsigned short* As, unsigned short* Bs,
                    f32x4 (&acc)[4][4]) {
  const int t = threadIdx.x;
  const int w = t >> 6, lane = t & 63;
  const int wr = w >> 1, wc = w & 1;
  const int l15 = lane & 15, l4 = lane >> 4;
  const int srow = t >> 3, sph = t & 7;
  for (int kt = 0; kt < K; kt += 64) {
#pragma unroll
    for (int i = 0; i < 4; ++i) {
      int row = i * 32 + srow;
      int slog = sph ^ (row & 7);
      async16(A + (size_t)(m0 + row) * K + kt + slog * 8, (char*)As + i * 4096 + w * 1024);
      async16(Bm + (size_t)(n0 + row) * K + kt + slog * 8, (char*)Bs + i * 4096 + w * 1024);
    }
    __syncthreads();
#pragma unroll
    for (int ks = 0; ks < 2; ++ks) {
      short8 af[4], bfv[4];
#pragma unroll
      for (int m = 0; m < 4; ++m) {
        int row = wr * 64 + m * 16 + l15;
        int slog = ks * 4 + l4;
        af[m] = *(const short8*)&As[row * 64 + ((slog ^ (row & 7)) << 3)];
      }
#pragma unroll
      for (int n = 0; n < 4; ++n) {
        int row = wc * 64 + n * 16 + l15;
        int slog = ks * 4 + l4;
        bfv[n] = *(const short8*)&Bs[row * 64 + ((slog ^ (row & 7)) << 3)];
      }
#pragma unroll
      for (int m = 0; m < 4; ++m)
#pragma unroll
        for (int n = 0; n < 4; ++n)
          acc[m][n] = __builtin_amdgcn_mfma_f32_16x16x32_bf16(af[m], bfv[n], acc[m][n], 0, 0, 0);
    }
    __syncthreads();
  }
}

// MODE 0: out = acc + bias (QKV). MODE 1: gelu(acc+bias) (FFN1). MODE 2: acc+bias+res (FFN2).
template <int MODE>
__global__ __launch_bounds__(256, 2) void k_gemm_act(
    const unsigned short* __restrict__ A, const unsigned short* __restrict__ W,
    const float* __restrict__ bias, const unsigned short* __restrict__ res,
    unsigned short* __restrict__ out, int K, int N) {
  __shared__ unsigned short As[128 * 64], Bs[128 * 64];
  const int m0 = blockIdx.x * 128, n0 = blockIdx.y * 128;
  f32x4 acc[4][4] = {};
  gemm_core(A, W, K, m0, n0, As, Bs, acc);
  const int t = threadIdx.x, w = t >> 6, lane = t & 63;
  const int wr = w >> 1, wc = w & 1, l15 = lane & 15, l4 = lane >> 4;
#pragma unroll
  for (int n = 0; n < 4; ++n) {
    int col = n0 + wc * 64 + n * 16 + l15;
    float bn = bias[col];
#pragma unroll
    for (int m = 0; m < 4; ++m) {
      int rowb = m0 + wr * 64 + m * 16 + l4 * 4;
#pragma unroll
      for (int q = 0; q < 4; ++q) {
        size_t idx = (size_t)(rowb + q) * N + col;
        float v = acc[m][n][q] + bn;
        if (MODE == 1) v = gelu_exact(v);
        if (MODE == 2) v += b2f(res[idx]);
        out[idx] = f2b(v);
      }
    }
  }
}

// Final: out[b,c,n] = wo@U + bo + xo (xo recomputed fp32 from x_opt + saved stats)
__global__ __launch_bounds__(256, 2) void k_gemm_out(
    const unsigned short* __restrict__ Wo, const unsigned short* __restrict__ U,
    const float* __restrict__ bo, const float* __restrict__ xopt,
    const float* __restrict__ meanG, const float* __restrict__ rstdG,
    const float* __restrict__ lnw, const float* __restrict__ lnb,
    float* __restrict__ out) {
  __shared__ unsigned short As[128 * 64], Bs[128 * 64];
  const int b = blockIdx.z;
  const int m0 = blockIdx.x * 128, n0 = blockIdx.y * 128;
  const unsigned short* Ub = U + (size_t)b * HWn * Cn;
  f32x4 acc[4][4] = {};
  gemm_core(Wo, Ub, 512, m0, n0, As, Bs, acc);
  const int t = threadIdx.x, w = t >> 6, lane = t & 63;
  const int wr = w >> 1, wc = w & 1, l15 = lane & 15, l4 = lane >> 4;
#pragma unroll
  for (int n = 0; n < 4; ++n) {
    int pix = n0 + wc * 64 + n * 16 + l15;
    float mn = meanG[b * HWn + pix], rs = rstdG[b * HWn + pix];
#pragma unroll
    for (int m = 0; m < 4; ++m) {
#pragma unroll
      for (int q = 0; q < 4; ++q) {
        int c = m0 + wr * 64 + m * 16 + l4 * 4 + q;
        size_t idx = (size_t)(b * Cn + c) * HWn + pix;
        float xo = (xopt[idx] - mn) * rs * lnw[c] + lnb[c];
        out[idx] = acc[m][n][q] + bo[c] + xo;
      }
    }
  }
}

// Z = V_head @ P  (M=128 pixels, N=64, K=64), epilogue adds z_opt (= XO, same layout)
__global__ __launch_bounds__(256, 2) void k_z(
    const unsigned short* __restrict__ V, const unsigned short* __restrict__ PT,
    const unsigned short* __restrict__ XO, unsigned short* __restrict__ ZS) {
  __shared__ unsigned short As[128 * 64], Bs[64 * 64];
  const int mt = blockIdx.x, bh = blockIdx.y, b = bh >> 3, h = bh & 7;
  const int t = threadIdx.x, w = t >> 6, lane = t & 63;
  const int wr = w >> 1, wc = w & 1, l15 = lane & 15, l4 = lane >> 4;
  const int srow = t >> 3, sph = t & 7;
#pragma unroll
  for (int i = 0; i < 4; ++i) {
    int row = i * 32 + srow;
    int slog = sph ^ (row & 7);
    async16(V + (size_t)(b * HWn + mt * 128 + row) * Cn + h * 64 + slog * 8,
            (char*)As + i * 4096 + w * 1024);
  }
#pragma unroll
  for (int i = 0; i < 2; ++i) {
    int row = i * 32 + srow;
    int slog = sph ^ (row & 7);
    async16(PT + (size_t)bh * 4096 + row * 64 + slog * 8, (char*)Bs + i * 4096 + w * 1024);
  }
  __syncthreads();
  f32x4 acc[4][2] = {};
#pragma unroll
  for (int ks = 0; ks < 2; ++ks) {
    short8 af[4], bfv[2];
#pragma unroll
    for (int m = 0; m < 4; ++m) {
      int row = wr * 64 + m * 16 + l15;
      int slog = ks * 4 + l4;
      af[m] = *(const short8*)&As[row * 64 + ((slog ^ (row & 7)) << 3)];
    }
#pragma unroll
    for (int n = 0; n < 2; ++n) {
      int row = wc * 32 + n * 16 + l15;
      int slog = ks * 4 + l4;
      bfv[n] = *(const short8*)&Bs[row * 64 + ((slog ^ (row & 7)) << 3)];
    }
#pragma unroll
    for (int m = 0; m < 4; ++m)
#pragma unroll
      for (int n = 0; n < 2; ++n)
        acc[m][n] = __builtin_amdgcn_mfma_f32_16x16x32_bf16(af[m], bfv[n], acc[m][n], 0, 0, 0);
  }
#pragma unroll
  for (int n = 0; n < 2; ++n) {
    int e = wc * 32 + n * 16 + l15;
#pragma unroll
    for (int m = 0; m < 4; ++m) {
#pragma unroll
      for (int q = 0; q < 4; ++q) {
        int rowp = mt * 128 + wr * 64 + m * 16 + l4 * 4 + q;
        size_t idx = (size_t)(b * HWn + rowp) * Cn + h * 64 + e;
        ZS[idx] = f2b(acc[m][n][q] + b2f(XO[idx]));
      }
    }
  }
}

// LayerNorm over C per pixel; writes transposed bf16 [pixel, C] via LDS stash.
template <bool STATS>
__global__ __launch_bounds__(256, 2) void k_ln(
    const float* __restrict__ x, const float* __restrict__ lw, const float* __restrict__ lb,
    unsigned short* __restrict__ out, float* __restrict__ meanG, float* __restrict__ rstdG) {
  __shared__ unsigned short stash[512 * 34];  // [c][32 pixels], stride 34 (68B) vs bank conflicts
  __shared__ float redS[256 * 4], redQ[256 * 4];
  __shared__ float meanS[32], rstdS[32], wS[512], bS[512];
  const int b = blockIdx.y, n0 = blockIdx.x * 32;
  const int t = threadIdx.x;
  wS[t] = lw[t]; wS[t + 256] = lw[t + 256];
  bS[t] = lb[t]; bS[t + 256] = lb[t + 256];
  const int cg = t >> 3, pq = t & 7;
  float sum[4] = {}, sq[4] = {};
  for (int r = 0; r < 16; ++r) {
    int c = r * 32 + cg;
    f32x4 v = *(const f32x4*)(x + (size_t)(b * Cn + c) * HWn + n0 + pq * 4);
#pragma unroll
    for (int j = 0; j < 4; ++j) { sum[j] += v[j]; sq[j] += v[j] * v[j]; }
    u16x2 h0 = {f2b(v[0]), f2b(v[1])};
    u16x2 h1 = {f2b(v[2]), f2b(v[3])};
    *(u16x2*)&stash[c * 34 + pq * 4] = h0;
    *(u16x2*)&stash[c * 34 + pq * 4 + 2] = h1;
  }
#pragma unroll
  for (int j = 0; j < 4; ++j) { redS[t * 4 + j] = sum[j]; redQ[t * 4 + j] = sq[j]; }
  __syncthreads();
  if (t < 32) {
    float s = 0.f, qq = 0.f;
    int pqq = t >> 2, j = t & 3;
    for (int g = 0; g < 32; ++g) {
      s += redS[(g * 8 + pqq) * 4 + j];
      qq += redQ[(g * 8 + pqq) * 4 + j];
    }
    float mean = s * (1.0f / 512.0f);
    float var = qq * (1.0f / 512.0f) - mean * mean;
    float rstd = rsqrtf(var + 1e-5f);
    meanS[t] = mean; rstdS[t] = rstd;
    if (STATS) { meanG[b * HWn + n0 + t] = mean; rstdG[b * HWn + n0 + t] = rstd; }
  }
  __syncthreads();
  const int p = t >> 3, cs = t & 7;
  float mn = meanS[p], rs = rstdS[p];
  for (int ch = 0; ch < 4; ++ch) {
    u16x8 o0, o1;
#pragma unroll
    for (int j = 0; j < 16; ++j) {
      int c = ch * 128 + cs * 16 + j;
      float xv = b2f(stash[c * 34 + p]);
      unsigned short r2 = f2b((xv - mn) * rs * wS[c] + bS[c]);
      if (j < 8) o0[j] = r2; else o1[j - 8] = r2;
    }
    size_t base = (size_t)(b * HWn + n0 + p) * Cn + ch * 128 + cs * 16;
    *(u16x8*)&out[base] = o0;
    *(u16x8*)&out[base + 8] = o1;
  }
}

// column sq-norms of Q/K over spatial axis (per (b, channel))
__global__ __launch_bounds__(256, 2) void k_sqnorm(
    const unsigned short* __restrict__ Q, const unsigned short* __restrict__ Kb,
    float* __restrict__ sqQ, float* __restrict__ sqK) {
  const int cb = blockIdx.x, ns = blockIdx.y, z = blockIdx.z;
  const int b = z >> 1;
  const unsigned short* src = (z & 1) ? Kb : Q;
  float* dst = (z & 1) ? sqK : sqQ;
  const int t = threadIdx.x;
  const int c4 = (t & 15) * 4, rg = t >> 4;
  float acc[4] = {};
  for (int r = 0; r < 32; ++r) {
    int n = ns * 512 + r * 16 + rg;
    u16x4 v = *(const u16x4*)(src + (size_t)(b * HWn + n) * Cn + cb * 64 + c4);
#pragma unroll
    for (int j = 0; j < 4; ++j) { float f = b2f(v[j]); acc[j] += f * f; }
  }
  __shared__ float red[256 * 4];
#pragma unroll
  for (int j = 0; j < 4; ++j) red[t * 4 + j] = acc[j];
  __syncthreads();
  if (t < 64) {
    int cq = t >> 2, j = t & 3;
    float s = 0.f;
    for (int g = 0; g < 16; ++g) s += red[(g * 16 + cq) * 4 + j];
    atomicAdd(&dst[b * Cn + cb * 64 + cq * 4 + j], s);
  }
}

// raw Gram partials: Praw[bh][d][e] += sum_n Q[n,d]*K[n,e]  (512-n slice per block)
__global__ __launch_bounds__(256, 2) void k_attn(
    const unsigned short* __restrict__ Q, const unsigned short* __restrict__ Kb,
    float* __restrict__ Praw) {
  __shared__ float Qs[64 * 64], Ks[64 * 64];
  const int bh = blockIdx.x, ns = blockIdx.y, b = bh >> 3, h = bh & 7;
  const int t = threadIdx.x;
  const int d0 = (t & 15) * 4, e0 = (t >> 4) * 4;
  float a[4][4] = {};
  for (int ch = 0; ch < 8; ++ch) {
    int n0 = ns * 512 + ch * 64;
    __syncthreads();
#pragma unroll
    for (int i = 0; i < 2; ++i) {
      int row = i * 32 + (t >> 3);
      int c8 = (t & 7) * 8;
      u16x8 vq = *(const u16x8*)(Q + (size_t)(b * HWn + n0 + row) * Cn + h * 64 + c8);
      u16x8 vk = *(const u16x8*)(Kb + (size_t)(b * HWn + n0 + row) * Cn + h * 64 + c8);
      f32x4 q0, q1, k0, k1;
#pragma unroll
      for (int j = 0; j < 4; ++j) {
        q0[j] = b2f(vq[j]); q1[j] = b2f(vq[j + 4]);
        k0[j] = b2f(vk[j]); k1[j] = b2f(vk[j + 4]);
      }
      *(f32x4*)&Qs[row * 64 + c8] = q0; *(f32x4*)&Qs[row * 64 + c8 + 4] = q1;
      *(f32x4*)&Ks[row * 64 + c8] = k0; *(f32x4*)&Ks[row * 64 + c8 + 4] = k1;
    }
    __syncthreads();
    for (int n = 0; n < 64; ++n) {
      f32x4 qv = *(const f32x4*)&Qs[n * 64 + d0];
      f32x4 kv = *(const f32x4*)&Ks[n * 64 + e0];
#pragma unroll
      for (int i = 0; i < 4; ++i)
#pragma unroll
        for (int j = 0; j < 4; ++j) a[i][j] += qv[i] * kv[j];
    }
  }
#pragma unroll
  for (int i = 0; i < 4; ++i)
#pragma unroll
    for (int j = 0; j < 4; ++j)
      atomicAdd(&Praw[(size_t)(bh * 64 + d0 + i) * 64 + e0 + j], a[i][j]);
}

// scale by rq*rk/8, row softmax, store P^T bf16
__global__ void k_softmax(const float* __restrict__ Praw, const float* __restrict__ sqQ,
                          const float* __restrict__ sqK, unsigned short* __restrict__ PT) {
  __shared__ float P2[64 * 65];
  const int bh = blockIdx.x, b = bh >> 3, h = bh & 7;
  const int lane = threadIdx.x;
  float rq = 1.0f / fmaxf(sqrtf(sqQ[b * Cn + h * 64 + lane]), 1e-12f);
  float rk = 1.0f / fmaxf(sqrtf(sqK[b * Cn + h * 64 + lane]), 1e-12f);
  for (int d = 0; d < 64; ++d) {
    float rqd = __shfl(rq, d, 64);
    float v = Praw[(size_t)(bh * 64 + d) * 64 + lane] * (rqd * rk * 0.125f);
    float m = v;
    for (int o = 32; o > 0; o >>= 1) m = fmaxf(m, __shfl_xor(m, o, 64));
    float p = __expf(v - m);
    float s = p;
    for (int o = 32; o > 0; o >>= 1) s += __shfl_xor(s, o, 64);
    P2[d * 65 + lane] = p / s;
  }
  __syncthreads();
  for (int e = 0; e < 64; ++e) {
    PT[(size_t)(bh * 64 + e) * 64 + lane] = f2b(P2[lane * 65 + e]);
  }
}

// weight prep: fp32->bf16 converts
__global__ void k_cvt4(const float* __restrict__ s0, const float* __restrict__ s1,
                       const float* __restrict__ s2, const float* __restrict__ s3,
                       unsigned short* __restrict__ d0, unsigned short* __restrict__ d1,
                       unsigned short* __restrict__ d2, unsigned short* __restrict__ d3) {
  const int mat = blockIdx.x >> 8, chunk = blockIdx.x & 255;
  const float* s = mat == 0 ? s0 : mat == 1 ? s1 : mat == 2 ? s2 : s3;
  unsigned short* d = mat == 0 ? d0 : mat == 1 ? d1 : mat == 2 ? d2 : d3;
  int idx = chunk * 1024 + threadIdx.x * 4;
  f32x4 v = *(const f32x4*)(s + idx);
  u16x4 o = {f2b(v[0]), f2b(v[1]), f2b(v[2]), f2b(v[3])};
  *(u16x4*)(d + idx) = o;
}

// weight prep: transposed bf16 copies of w1 [512,1024] and w2 [1024,512]
__global__ void k_trans(const float* __restrict__ w1, const float* __restrict__ w2,
                        unsigned short* __restrict__ W1T, unsigned short* __restrict__ W2T) {
  __shared__ float tile[32][33];
  const float* src; unsigned short* dst; int R, C, r0, c0;
  int bid = blockIdx.x;
  if (bid < 512) { src = w1; dst = W1T; R = 512; C = 1024; r0 = (bid >> 5) * 32; c0 = (bid & 31) * 32; }
  else { bid -= 512; src = w2; dst = W2T; R = 1024; C = 512; r0 = (bid >> 4) * 32; c0 = (bid & 15) * 32; }
  const int tx = threadIdx.x & 31, ty = threadIdx.x >> 5;
#pragma unroll
  for (int i = 0; i < 4; ++i)
    tile[ty + i * 8][tx] = src[(size_t)(r0 + ty + i * 8) * C + c0 + tx];
  __syncthreads();
#pragma unroll
  for (int i = 0; i < 4; ++i)
    dst[(size_t)(c0 + ty + i * 8) * R + r0 + tx] = f2b(tile[tx][ty + i * 8]);
}

extern "C" void kernel_launch(void* const* d_in, const int* in_sizes, int n_in,
                              void* d_out, int out_size, void* d_ws, size_t ws_size,
                              hipStream_t stream) {
  const float* x_opt = (const float*)d_in[0];
  const float* x_sar = (const float*)d_in[1];
  const float* ln_o_w = (const float*)d_in[2];
  const float* ln_o_b = (const float*)d_in[3];
  const float* ln_s_w = (const float*)d_in[4];
  const float* ln_s_b = (const float*)d_in[5];
  const float* wq = (const float*)d_in[6];
  const float* bq = (const float*)d_in[7];
  const float* wk = (const float*)d_in[8];
  const float* bk = (const float*)d_in[9];
  const float* wv = (const float*)d_in[10];
  const float* bv = (const float*)d_in[11];
  const float* w1 = (const float*)d_in[12];
  const float* b1 = (const float*)d_in[13];
  const float* w2 = (const float*)d_in[14];
  const float* b2 = (const float*)d_in[15];
  const float* wo = (const float*)d_in[16];
  const float* bo = (const float*)d_in[17];
  float* out = (float*)d_out;

  char* ws = (char*)d_ws;
  const size_t S = (size_t)Mtot * Cn * 2;  // 33,554,432
  unsigned short* XO = (unsigned short*)(ws);
  unsigned short* XS = (unsigned short*)(ws + S);
  unsigned short* Qb = (unsigned short*)(ws + 2 * S);
  unsigned short* Kb = (unsigned short*)(ws + 3 * S);
  unsigned short* Vb = (unsigned short*)(ws + 4 * S);
  unsigned short* ZS = (unsigned short*)(ws + 5 * S);
  unsigned short* H1 = Qb;  // alias: Q+K region (Q,K dead after attention)
  unsigned short* Ub = XS;  // alias: XS dead after K/V GEMMs
  char* E = ws + 6 * S;
  unsigned short* PT = (unsigned short*)(E);                       // 524288
  float* Praw = (float*)(E + 524288);                              // 1048576
  float* sqQ = (float*)(E + 524288 + 1048576);                     // 16384
  float* sqK = (float*)(E + 524288 + 1048576 + 16384);             // 16384
  float* meanG = (float*)(E + 524288 + 1048576 + 32768);           // 131072
  float* rstdG = (float*)(E + 524288 + 1048576 + 32768 + 131072);  // 131072
  char* Wb = E + 1867776;
  unsigned short* WQ = (unsigned short*)(Wb);
  unsigned short* WK = (unsigned short*)(Wb + 524288);
  unsigned short* WV = (unsigned short*)(Wb + 1048576);
  unsigned short* WO = (unsigned short*)(Wb + 1572864);
  unsigned short* W1T = (unsigned short*)(Wb + 2097152);
  unsigned short* W2T = (unsigned short*)(Wb + 2097152 + 1048576);

  // zero the atomic targets (Praw, sqQ, sqK are contiguous)
  hipMemsetAsync(E + 524288, 0, 1048576 + 32768, stream);

  k_cvt4<<<1024, 256, 0, stream>>>(wq, wk, wv, wo, WQ, WK, WV, WO);
  k_trans<<<1024, 256, 0, stream>>>(w1, w2, W1T, W2T);

  k_ln<true><<<dim3(128, Bn), 256, 0, stream>>>(x_opt, ln_o_w, ln_o_b, XO, meanG, rstdG);
  k_ln<false><<<dim3(128, Bn), 256, 0, stream>>>(x_sar, ln_s_w, ln_s_b, XS, nullptr, nullptr);

  k_gemm_act<0><<<dim3(256, 4), 256, 0, stream>>>(XO, WQ, bq, nullptr, Qb, 512, 512);
  k_gemm_act<0><<<dim3(256, 4), 256, 0, stream>>>(XS, WK, bk, nullptr, Kb, 512, 512);
  k_gemm_act<0><<<dim3(256, 4), 256, 0, stream>>>(XS, WV, bv, nullptr, Vb, 512, 512);

  k_sqnorm<<<dim3(8, 8, 16), 256, 0, stream>>>(Qb, Kb, sqQ, sqK);
  k_attn<<<dim3(64, 8), 256, 0, stream>>>(Qb, Kb, Praw);
  k_softmax<<<64, 64, 0, stream>>>(Praw, sqQ, sqK, PT);
  k_z<<<dim3(32, 64), 256, 0, stream>>>(Vb, PT, XO, ZS);

  k_gemm_act<1><<<dim3(256, 8), 256, 0, stream>>>(ZS, W1T, b1, nullptr, H1, 512, 1024);
  k_gemm_act<2><<<dim3(256, 4), 256, 0, stream>>>(H1, W2T, b2, ZS, Ub, 1024, 512);
  k_gemm_out<<<dim3(4, 32, 8), 256, 0, stream>>>(WO, Ub, bo, x_opt, meanG, rstdG,
                                                 ln_o_w, ln_o_b, out);
}

// Round 2
// 421.393 us; speedup vs baseline: 1.0319x; 1.0319x over previous
//
#include <hip/hip_runtime.h>
#include <cstdint>
#include <cstddef>

#define DEVI __device__ __forceinline__

typedef __attribute__((ext_vector_type(8))) short short8;
typedef __attribute__((ext_vector_type(4))) float f32x4;
typedef __attribute__((ext_vector_type(2))) unsigned short u16x2;
typedef __attribute__((ext_vector_type(4))) unsigned short u16x4;
typedef __attribute__((ext_vector_type(8))) unsigned short u16x8;

#define Bn 8
#define Cn 512
#define HWn 4096
#define Mtot 32768

DEVI float b2f(unsigned short u) {
  union { uint32_t u; float f; } c; c.u = ((uint32_t)u) << 16; return c.f;
}
DEVI unsigned short f2b(float f) {
  union { float f; uint32_t u; } c; c.f = f;
  uint32_t u = c.u + 0x7fffu + ((c.u >> 16) & 1u);
  return (unsigned short)(u >> 16);
}
// tanh-form gelu; |err| vs exact erf-gelu ~1e-3, well under bf16 output noise
DEVI float gelu_fast(float x) {
  float y = 0.7978845608f * (x + 0.044715f * x * x * x);
  float e = __expf(2.0f * y);
  float t = 1.0f - 2.0f / (e + 1.0f);
  return 0.5f * x * (1.0f + t);
}

DEVI void async16(const void* g, void* l) {
  __builtin_amdgcn_global_load_lds((const __attribute__((address_space(1))) uint32_t*)g,
                                   (__attribute__((address_space(3))) uint32_t*)l, 16, 0, 0);
}

// ---------------- NT GEMM core: C[128x128] = A[M,K] * B[N,K]^T, bf16 in, f32 acc.
// LDS tiles [128 rows][64 k] bf16, rows 128B = 8 x 16B slots, XOR-swizzle slot ^= (row&7).
DEVI void gemm_core(const unsigned short* __restrict__ A, const unsigned short* __restrict__ Bm,
                    int K, int m0, int n0, unsigned short* As, unsigned short* Bs,
                    f32x4 (&acc)[4][4]) {
  const int t = threadIdx.x;
  const int w = t >> 6, lane = t & 63;
  const int wr = w >> 1, wc = w & 1;
  const int l15 = lane & 15, l4 = lane >> 4;
  const int srow = t >> 3, sph = t & 7;
  for (int kt = 0; kt < K; kt += 64) {
#pragma unroll
    for (int i = 0; i < 4; ++i) {
      int row = i * 32 + srow;
      int slog = sph ^ (row & 7);
      async16(A + (size_t)(m0 + row) * K + kt + slog * 8, (char*)As + i * 4096 + w * 1024);
      async16(Bm + (size_t)(n0 + row) * K + kt + slog * 8, (char*)Bs + i * 4096 + w * 1024);
    }
    __syncthreads();
#pragma unroll
    for (int ks = 0; ks < 2; ++ks) {
      short8 af[4], bfv[4];
#pragma unroll
      for (int m = 0; m < 4; ++m) {
        int row = wr * 64 + m * 16 + l15;
        int slog = ks * 4 + l4;
        af[m] = *(const short8*)&As[row * 64 + ((slog ^ (row & 7)) << 3)];
      }
#pragma unroll
      for (int n = 0; n < 4; ++n) {
        int row = wc * 64 + n * 16 + l15;
        int slog = ks * 4 + l4;
        bfv[n] = *(const short8*)&Bs[row * 64 + ((slog ^ (row & 7)) << 3)];
      }
#pragma unroll
      for (int m = 0; m < 4; ++m)
#pragma unroll
        for (int n = 0; n < 4; ++n)
          acc[m][n] = __builtin_amdgcn_mfma_f32_16x16x32_bf16(af[m], bfv[n], acc[m][n], 0, 0, 0);
    }
    __syncthreads();
  }
}

// MODE 0: out = acc + bias. MODE 1: gelu(acc+bias). MODE 2: acc+bias+res.
// Epilogue: acc -> LDS bf16 tile -> coalesced u16x8 stores (8 lanes = 128B contiguous).
template <int MODE>
__global__ __launch_bounds__(256, 2) void k_gemm_act(
    const unsigned short* __restrict__ A, const unsigned short* __restrict__ W,
    const float* __restrict__ bias, const float* __restrict__ bias2, int nsplit,
    const unsigned short* __restrict__ res,
    unsigned short* __restrict__ out, int K, int N) {
  __shared__ __align__(16) char smem[34816];
  unsigned short* As = (unsigned short*)smem;
  unsigned short* Bs = (unsigned short*)(smem + 16384);
  const int m0 = blockIdx.x * 128, n0 = blockIdx.y * 128;
  f32x4 acc[4][4] = {};
  gemm_core(A, W, K, m0, n0, As, Bs, acc);
  const int t = threadIdx.x, w = t >> 6, lane = t & 63;
  const int wr = w >> 1, wc = w & 1, l15 = lane & 15, l4 = lane >> 4;
  unsigned short* Cs = (unsigned short*)smem;  // [128][136]
#pragma unroll
  for (int n = 0; n < 4; ++n) {
    int cn = wc * 64 + n * 16 + l15;
    int col = n0 + cn;
    float bn = (col < nsplit) ? bias[col] : bias2[col - nsplit];
#pragma unroll
    for (int m = 0; m < 4; ++m) {
      int rb = wr * 64 + m * 16 + l4 * 4;
#pragma unroll
      for (int q = 0; q < 4; ++q) {
        float v = acc[m][n][q] + bn;
        if (MODE == 1) v = gelu_fast(v);
        Cs[(rb + q) * 136 + cn] = f2b(v);
      }
    }
  }
  __syncthreads();
#pragma unroll
  for (int pass = 0; pass < 4; ++pass) {
    int r = pass * 32 + (t >> 3);
    int c = (t & 7) * 8;
    u16x8 v0 = *(const u16x8*)&Cs[r * 136 + c];
    u16x8 v1 = *(const u16x8*)&Cs[r * 136 + 64 + c];
    size_t base = (size_t)(m0 + r) * N + n0;
    if (MODE == 2) {
      u16x8 r0 = *(const u16x8*)&res[base + c];
      u16x8 r1 = *(const u16x8*)&res[base + 64 + c];
#pragma unroll
      for (int j = 0; j < 8; ++j) {
        v0[j] = f2b(b2f(v0[j]) + b2f(r0[j]));
        v1[j] = f2b(b2f(v1[j]) + b2f(r1[j]));
      }
    }
    *(u16x8*)&out[base + c] = v0;
    *(u16x8*)&out[base + 64 + c] = v1;
  }
}

// Final: out[b,c,n] = wo@U + bo + xo (xo recomputed fp32 from x_opt + saved stats)
__global__ __launch_bounds__(256, 2) void k_gemm_out(
    const unsigned short* __restrict__ Wo, const unsigned short* __restrict__ U,
    const float* __restrict__ bo, const float* __restrict__ xopt,
    const float* __restrict__ meanG, const float* __restrict__ rstdG,
    const float* __restrict__ lnw, const float* __restrict__ lnb,
    float* __restrict__ out) {
  __shared__ __align__(16) char smem[32768];
  unsigned short* As = (unsigned short*)smem;
  unsigned short* Bs = (unsigned short*)(smem + 16384);
  const int b = blockIdx.z;
  const int m0 = blockIdx.x * 128, n0 = blockIdx.y * 128;
  const unsigned short* Ub = U + (size_t)b * HWn * Cn;
  f32x4 acc[4][4] = {};
  gemm_core(Wo, Ub, 512, m0, n0, As, Bs, acc);
  const int t = threadIdx.x, w = t >> 6, lane = t & 63;
  const int wr = w >> 1, wc = w & 1, l15 = lane & 15, l4 = lane >> 4;
#pragma unroll
  for (int n = 0; n < 4; ++n) {
    int pix = n0 + wc * 64 + n * 16 + l15;
    float mn = meanG[b * HWn + pix], rs = rstdG[b * HWn + pix];
#pragma unroll
    for (int m = 0; m < 4; ++m) {
#pragma unroll
      for (int q = 0; q < 4; ++q) {
        int c = m0 + wr * 64 + m * 16 + l4 * 4 + q;
        size_t idx = (size_t)(b * Cn + c) * HWn + pix;
        float xo = (xopt[idx] - mn) * rs * lnw[c] + lnb[c];
        out[idx] = acc[m][n][q] + bo[c] + xo;
      }
    }
  }
}

// Z = V_head @ P  (M=128 pixels, N=64, K=64), epilogue adds z_opt (= XO, same layout)
__global__ __launch_bounds__(256, 2) void k_z(
    const unsigned short* __restrict__ V, int ldv, const unsigned short* __restrict__ PT,
    const unsigned short* __restrict__ XO, unsigned short* __restrict__ ZS) {
  __shared__ __align__(16) char smem[24576];
  unsigned short* As = (unsigned short*)smem;
  unsigned short* Bs = (unsigned short*)(smem + 16384);
  const int mt = blockIdx.x, bh = blockIdx.y, b = bh >> 3, h = bh & 7;
  const int t = threadIdx.x, w = t >> 6, lane = t & 63;
  const int wr = w >> 1, wc = w & 1, l15 = lane & 15, l4 = lane >> 4;
  const int srow = t >> 3, sph = t & 7;
#pragma unroll
  for (int i = 0; i < 4; ++i) {
    int row = i * 32 + srow;
    int slog = sph ^ (row & 7);
    async16(V + (size_t)(b * HWn + mt * 128 + row) * ldv + h * 64 + slog * 8,
            (char*)As + i * 4096 + w * 1024);
  }
#pragma unroll
  for (int i = 0; i < 2; ++i) {
    int row = i * 32 + srow;
    int slog = sph ^ (row & 7);
    async16(PT + (size_t)bh * 4096 + row * 64 + slog * 8, (char*)Bs + i * 4096 + w * 1024);
  }
  __syncthreads();
  f32x4 acc[4][2] = {};
#pragma unroll
  for (int ks = 0; ks < 2; ++ks) {
    short8 af[4], bfv[2];
#pragma unroll
    for (int m = 0; m < 4; ++m) {
      int row = wr * 64 + m * 16 + l15;
      int slog = ks * 4 + l4;
      af[m] = *(const short8*)&As[row * 64 + ((slog ^ (row & 7)) << 3)];
    }
#pragma unroll
    for (int n = 0; n < 2; ++n) {
      int row = wc * 32 + n * 16 + l15;
      int slog = ks * 4 + l4;
      bfv[n] = *(const short8*)&Bs[row * 64 + ((slog ^ (row & 7)) << 3)];
    }
#pragma unroll
    for (int m = 0; m < 4; ++m)
#pragma unroll
      for (int n = 0; n < 2; ++n)
        acc[m][n] = __builtin_amdgcn_mfma_f32_16x16x32_bf16(af[m], bfv[n], acc[m][n], 0, 0, 0);
  }
  __syncthreads();
  unsigned short* Cs = (unsigned short*)smem;  // [128][72]
#pragma unroll
  for (int n = 0; n < 2; ++n) {
    int e = wc * 32 + n * 16 + l15;
#pragma unroll
    for (int m = 0; m < 4; ++m) {
      int rb = wr * 64 + m * 16 + l4 * 4;
#pragma unroll
      for (int q = 0; q < 4; ++q) Cs[(rb + q) * 72 + e] = f2b(acc[m][n][q]);
    }
  }
  __syncthreads();
#pragma unroll
  for (int pass = 0; pass < 4; ++pass) {
    int r = pass * 32 + (t >> 3);
    int c = (t & 7) * 8;
    u16x8 v = *(const u16x8*)&Cs[r * 72 + c];
    size_t idx = (size_t)(b * HWn + mt * 128 + r) * Cn + h * 64 + c;
    u16x8 xo = *(const u16x8*)&XO[idx];
#pragma unroll
    for (int j = 0; j < 8; ++j) v[j] = f2b(b2f(v[j]) + b2f(xo[j]));
    *(u16x8*)&ZS[idx] = v;
  }
}

// LayerNorm over C per pixel; writes transposed bf16 [pixel, C] via LDS stash.
template <bool STATS>
__global__ __launch_bounds__(256, 2) void k_ln(
    const float* __restrict__ x, const float* __restrict__ lw, const float* __restrict__ lb,
    unsigned short* __restrict__ out, float* __restrict__ meanG, float* __restrict__ rstdG) {
  __shared__ unsigned short stash[512 * 34];
  __shared__ float redS[256 * 4], redQ[256 * 4];
  __shared__ float meanS[32], rstdS[32], wS[512], bS[512];
  const int b = blockIdx.y, n0 = blockIdx.x * 32;
  const int t = threadIdx.x;
  wS[t] = lw[t]; wS[t + 256] = lw[t + 256];
  bS[t] = lb[t]; bS[t + 256] = lb[t + 256];
  const int cg = t >> 3, pq = t & 7;
  float sum[4] = {}, sq[4] = {};
  for (int r = 0; r < 16; ++r) {
    int c = r * 32 + cg;
    f32x4 v = *(const f32x4*)(x + (size_t)(b * Cn + c) * HWn + n0 + pq * 4);
#pragma unroll
    for (int j = 0; j < 4; ++j) { sum[j] += v[j]; sq[j] += v[j] * v[j]; }
    u16x2 h0 = {f2b(v[0]), f2b(v[1])};
    u16x2 h1 = {f2b(v[2]), f2b(v[3])};
    *(u16x2*)&stash[c * 34 + pq * 4] = h0;
    *(u16x2*)&stash[c * 34 + pq * 4 + 2] = h1;
  }
#pragma unroll
  for (int j = 0; j < 4; ++j) { redS[t * 4 + j] = sum[j]; redQ[t * 4 + j] = sq[j]; }
  __syncthreads();
  if (t < 32) {
    float s = 0.f, qq = 0.f;
    int pqq = t >> 2, j = t & 3;
    for (int g = 0; g < 32; ++g) {
      s += redS[(g * 8 + pqq) * 4 + j];
      qq += redQ[(g * 8 + pqq) * 4 + j];
    }
    float mean = s * (1.0f / 512.0f);
    float var = qq * (1.0f / 512.0f) - mean * mean;
    float rstd = rsqrtf(var + 1e-5f);
    meanS[t] = mean; rstdS[t] = rstd;
    if (STATS) { meanG[b * HWn + n0 + t] = mean; rstdG[b * HWn + n0 + t] = rstd; }
  }
  __syncthreads();
  const int p = t >> 3, cs = t & 7;
  float mn = meanS[p], rs = rstdS[p];
  for (int ch = 0; ch < 4; ++ch) {
    u16x8 o0, o1;
#pragma unroll
    for (int j = 0; j < 16; ++j) {
      int c = ch * 128 + cs * 16 + j;
      float xv = b2f(stash[c * 34 + p]);
      unsigned short r2 = f2b((xv - mn) * rs * wS[c] + bS[c]);
      if (j < 8) o0[j] = r2; else o1[j - 8] = r2;
    }
    size_t base = (size_t)(b * HWn + n0 + p) * Cn + ch * 128 + cs * 16;
    *(u16x8*)&out[base] = o0;
    *(u16x8*)&out[base + 8] = o1;
  }
}

// column sq-norms of Q/K over spatial axis (per (b, channel))
__global__ __launch_bounds__(256, 2) void k_sqnorm(
    const unsigned short* __restrict__ Q, int ldq,
    const unsigned short* __restrict__ Kb, int ldk,
    float* __restrict__ sqQ, float* __restrict__ sqK) {
  const int cb = blockIdx.x, ns = blockIdx.y, z = blockIdx.z;
  const int b = z >> 1;
  const unsigned short* src = (z & 1) ? Kb : Q;
  const int ld = (z & 1) ? ldk : ldq;
  float* dst = (z & 1) ? sqK : sqQ;
  const int t = threadIdx.x;
  const int c4 = (t & 15) * 4, rg = t >> 4;
  float acc[4] = {};
  for (int r = 0; r < 32; ++r) {
    int n = ns * 512 + r * 16 + rg;
    u16x4 v = *(const u16x4*)(src + (size_t)(b * HWn + n) * ld + cb * 64 + c4);
#pragma unroll
    for (int j = 0; j < 4; ++j) { float f = b2f(v[j]); acc[j] += f * f; }
  }
  __shared__ float red[256 * 4];
#pragma unroll
  for (int j = 0; j < 4; ++j) red[t * 4 + j] = acc[j];
  __syncthreads();
  if (t < 64) {
    int cq = t >> 2, j = t & 3;
    float s = 0.f;
    for (int g = 0; g < 16; ++g) s += red[(g * 16 + cq) * 4 + j];
    atomicAdd(&dst[b * Cn + cb * 64 + cq * 4 + j], s);
  }
}

// raw Gram partials: Praw[bh][d][e] += sum_n Q[n,d]*K[n,e]  (512-n slice per block)
__global__ __launch_bounds__(256, 2) void k_attn(
    const unsigned short* __restrict__ Q, int ldq,
    const unsigned short* __restrict__ Kb, int ldk,
    float* __restrict__ Praw) {
  __shared__ float Qs[64 * 64], Ks[64 * 64];
  const int bh = blockIdx.x, ns = blockIdx.y, b = bh >> 3, h = bh & 7;
  const int t = threadIdx.x;
  const int d0 = (t & 15) * 4, e0 = (t >> 4) * 4;
  float a[4][4] = {};
  for (int ch = 0; ch < 8; ++ch) {
    int n0 = ns * 512 + ch * 64;
    __syncthreads();
#pragma unroll
    for (int i = 0; i < 2; ++i) {
      int row = i * 32 + (t >> 3);
      int c8 = (t & 7) * 8;
      u16x8 vq = *(const u16x8*)(Q + (size_t)(b * HWn + n0 + row) * ldq + h * 64 + c8);
      u16x8 vk = *(const u16x8*)(Kb + (size_t)(b * HWn + n0 + row) * ldk + h * 64 + c8);
      f32x4 q0, q1, k0, k1;
#pragma unroll
      for (int j = 0; j < 4; ++j) {
        q0[j] = b2f(vq[j]); q1[j] = b2f(vq[j + 4]);
        k0[j] = b2f(vk[j]); k1[j] = b2f(vk[j + 4]);
      }
      *(f32x4*)&Qs[row * 64 + c8] = q0; *(f32x4*)&Qs[row * 64 + c8 + 4] = q1;
      *(f32x4*)&Ks[row * 64 + c8] = k0; *(f32x4*)&Ks[row * 64 + c8 + 4] = k1;
    }
    __syncthreads();
    for (int n = 0; n < 64; ++n) {
      f32x4 qv = *(const f32x4*)&Qs[n * 64 + d0];
      f32x4 kv = *(const f32x4*)&Ks[n * 64 + e0];
#pragma unroll
      for (int i = 0; i < 4; ++i)
#pragma unroll
        for (int j = 0; j < 4; ++j) a[i][j] += qv[i] * kv[j];
    }
  }
#pragma unroll
  for (int i = 0; i < 4; ++i)
#pragma unroll
    for (int j = 0; j < 4; ++j)
      atomicAdd(&Praw[(size_t)(bh * 64 + d0 + i) * 64 + e0 + j], a[i][j]);
}

// scale by rq*rk/8, row softmax, store P^T bf16
__global__ void k_softmax(const float* __restrict__ Praw, const float* __restrict__ sqQ,
                          const float* __restrict__ sqK, unsigned short* __restrict__ PT) {
  __shared__ float P2[64 * 65];
  const int bh = blockIdx.x, b = bh >> 3, h = bh & 7;
  const int lane = threadIdx.x;
  float rq = 1.0f / fmaxf(sqrtf(sqQ[b * Cn + h * 64 + lane]), 1e-12f);
  float rk = 1.0f / fmaxf(sqrtf(sqK[b * Cn + h * 64 + lane]), 1e-12f);
  for (int d = 0; d < 64; ++d) {
    float rqd = __shfl(rq, d, 64);
    float v = Praw[(size_t)(bh * 64 + d) * 64 + lane] * (rqd * rk * 0.125f);
    float m = v;
    for (int o = 32; o > 0; o >>= 1) m = fmaxf(m, __shfl_xor(m, o, 64));
    float p = __expf(v - m);
    float s = p;
    for (int o = 32; o > 0; o >>= 1) s += __shfl_xor(s, o, 64);
    P2[d * 65 + lane] = p / s;
  }
  __syncthreads();
  for (int e = 0; e < 64; ++e) {
    PT[(size_t)(bh * 64 + e) * 64 + lane] = f2b(P2[lane * 65 + e]);
  }
}

// weight prep: fp32->bf16 converts
__global__ void k_cvt4(const float* __restrict__ s0, const float* __restrict__ s1,
                       const float* __restrict__ s2, const float* __restrict__ s3,
                       unsigned short* __restrict__ d0, unsigned short* __restrict__ d1,
                       unsigned short* __restrict__ d2, unsigned short* __restrict__ d3) {
  const int mat = blockIdx.x >> 8, chunk = blockIdx.x & 255;
  const float* s = mat == 0 ? s0 : mat == 1 ? s1 : mat == 2 ? s2 : s3;
  unsigned short* d = mat == 0 ? d0 : mat == 1 ? d1 : mat == 2 ? d2 : d3;
  int idx = chunk * 1024 + threadIdx.x * 4;
  f32x4 v = *(const f32x4*)(s + idx);
  u16x4 o = {f2b(v[0]), f2b(v[1]), f2b(v[2]), f2b(v[3])};
  *(u16x4*)(d + idx) = o;
}

// weight prep: transposed bf16 copies of w1 [512,1024] and w2 [1024,512]
__global__ void k_trans(const float* __restrict__ w1, const float* __restrict__ w2,
                        unsigned short* __restrict__ W1T, unsigned short* __restrict__ W2T) {
  __shared__ float tile[32][33];
  const float* src; unsigned short* dst; int R, C, r0, c0;
  int bid = blockIdx.x;
  if (bid < 512) { src = w1; dst = W1T; R = 512; C = 1024; r0 = (bid >> 5) * 32; c0 = (bid & 31) * 32; }
  else { bid -= 512; src = w2; dst = W2T; R = 1024; C = 512; r0 = (bid >> 4) * 32; c0 = (bid & 15) * 32; }
  const int tx = threadIdx.x & 31, ty = threadIdx.x >> 5;
#pragma unroll
  for (int i = 0; i < 4; ++i)
    tile[ty + i * 8][tx] = src[(size_t)(r0 + ty + i * 8) * C + c0 + tx];
  __syncthreads();
#pragma unroll
  for (int i = 0; i < 4; ++i)
    dst[(size_t)(c0 + ty + i * 8) * R + r0 + tx] = f2b(tile[tx][ty + i * 8]);
}

extern "C" void kernel_launch(void* const* d_in, const int* in_sizes, int n_in,
                              void* d_out, int out_size, void* d_ws, size_t ws_size,
                              hipStream_t stream) {
  const float* x_opt = (const float*)d_in[0];
  const float* x_sar = (const float*)d_in[1];
  const float* ln_o_w = (const float*)d_in[2];
  const float* ln_o_b = (const float*)d_in[3];
  const float* ln_s_w = (const float*)d_in[4];
  const float* ln_s_b = (const float*)d_in[5];
  const float* wq = (const float*)d_in[6];
  const float* bq = (const float*)d_in[7];
  const float* wk = (const float*)d_in[8];
  const float* bk = (const float*)d_in[9];
  const float* wv = (const float*)d_in[10];
  const float* bv = (const float*)d_in[11];
  const float* w1 = (const float*)d_in[12];
  const float* b1 = (const float*)d_in[13];
  const float* w2 = (const float*)d_in[14];
  const float* b2 = (const float*)d_in[15];
  const float* wo = (const float*)d_in[16];
  const float* bo = (const float*)d_in[17];
  float* out = (float*)d_out;

  char* ws = (char*)d_ws;
  const size_t S = (size_t)Mtot * Cn * 2;  // 33,554,432
  unsigned short* XO = (unsigned short*)(ws);
  unsigned short* XS = (unsigned short*)(ws + S);
  unsigned short* Qb = (unsigned short*)(ws + 2 * S);
  unsigned short* KVb = (unsigned short*)(ws + 3 * S);  // [32768][1024]: K cols 0-511, V 512-1023
  unsigned short* ZS = (unsigned short*)(ws + 5 * S);
  unsigned short* H1 = Qb;  // alias: [2S,4S) — Q and K/V dead after attention
  unsigned short* Ub = XS;  // alias: XS dead after KV GEMM
  char* E = ws + 6 * S;
  unsigned short* PT = (unsigned short*)(E);                       // 524288
  float* Praw = (float*)(E + 524288);                              // 1048576
  float* sqQ = (float*)(E + 524288 + 1048576);                     // 16384
  float* sqK = (float*)(E + 524288 + 1048576 + 16384);             // 16384
  float* meanG = (float*)(E + 524288 + 1048576 + 32768);           // 131072
  float* rstdG = (float*)(E + 524288 + 1048576 + 32768 + 131072);  // 131072
  char* Wb = E + 1867776;
  unsigned short* WQ = (unsigned short*)(Wb);
  unsigned short* WKV = (unsigned short*)(Wb + 524288);  // 1MB: WK rows 0-511, WV rows 512-1023
  unsigned short* WO = (unsigned short*)(Wb + 1572864);
  unsigned short* W1T = (unsigned short*)(Wb + 2097152);
  unsigned short* W2T = (unsigned short*)(Wb + 2097152 + 1048576);

  const int BIG = 1 << 30;

  // zero the atomic targets (Praw, sqQ, sqK are contiguous)
  hipMemsetAsync(E + 524288, 0, 1048576 + 32768, stream);

  k_cvt4<<<1024, 256, 0, stream>>>(wq, wk, wv, wo, WQ, WKV, WKV + 262144, WO);
  k_trans<<<1024, 256, 0, stream>>>(w1, w2, W1T, W2T);

  k_ln<true><<<dim3(128, Bn), 256, 0, stream>>>(x_opt, ln_o_w, ln_o_b, XO, meanG, rstdG);
  k_ln<false><<<dim3(128, Bn), 256, 0, stream>>>(x_sar, ln_s_w, ln_s_b, XS, nullptr, nullptr);

  k_gemm_act<0><<<dim3(256, 4), 256, 0, stream>>>(XO, WQ, bq, bq, BIG, nullptr, Qb, 512, 512);
  k_gemm_act<0><<<dim3(256, 8), 256, 0, stream>>>(XS, WKV, bk, bv, 512, nullptr, KVb, 512, 1024);

  k_sqnorm<<<dim3(8, 8, 16), 256, 0, stream>>>(Qb, 512, KVb, 1024, sqQ, sqK);
  k_attn<<<dim3(64, 8), 256, 0, stream>>>(Qb, 512, KVb, 1024, Praw);
  k_softmax<<<64, 64, 0, stream>>>(Praw, sqQ, sqK, PT);
  k_z<<<dim3(32, 64), 256, 0, stream>>>(KVb + 512, 1024, PT, XO, ZS);

  k_gemm_act<1><<<dim3(256, 8), 256, 0, stream>>>(ZS, W1T, b1, b1, BIG, nullptr, H1, 512, 1024);
  k_gemm_act<2><<<dim3(256, 4), 256, 0, stream>>>(H1, W2T, b2, b2, BIG, ZS, Ub, 1024, 512);
  k_gemm_out<<<dim3(4, 32, 8), 256, 0, stream>>>(WO, Ub, bo, x_opt, meanG, rstdG,
                                                 ln_o_w, ln_o_b, out);
}